// Round 13
// baseline (131.734 us; speedup 1.0000x reference)
//
#include <hip/hip_runtime.h>

#define HW 256
#define CH 64
#define NPIX (4 * HW * HW)              // 262144 pixels
#define ENC_BYTES ((size_t)NPIX * 24)   // 12 u16 per pixel (9 used)
#define DM_OFF ((size_t)8 << 20)        // dm region at ws+8MB
#define DM_BYTES ((size_t)NPIX * 36)    // SoA: 9 planes x NPIX f32
#define WS_NEED (DM_OFF + DM_BYTES)

// ===================== Kernel A: address precompute (verified r2..r12) =====================
__global__ __launch_bounds__(256, 8) void DeformA_kernel(
    const float* __restrict__ gt,     // [256,256]
    const float* __restrict__ off,    // [4,256,256,18]
    unsigned short* __restrict__ enc) // [NPIX][12]
{
    const unsigned g = blockIdx.x * 256u + threadIdx.x;   // < NPIX*9
    const unsigned p = g / 9u;                             // magic-mul
    const int tap = (int)(g - p * 9u);
    const int i = (int)((p >> 8) & 255u);
    const int j = (int)(p & 255u);
    const int ky = tap / 3, kx = tap - ky * 3;

    const float2 o2 = *(const float2*)(off + (size_t)g * 2);

    const int iy = i + ky - 1, ix = j + kx - 1;
    const bool interior = (iy >= 0) & (iy < HW) & (ix >= 0) & (ix < HW);
    const int yi = interior ? iy : 0;
    const int xi = interior ? ix : 0;
    const float p_mask = (yi >= 1 && xi >= 1) ? gt[(yi - 1) * HW + (xi - 1)] : 0.f;

    const float yf = (float)yi, xf = (float)xi;
    const float yof = fminf(fmaxf(floorf(yf + o2.x), 0.f), 257.f);
    const float xof = fminf(fmaxf(floorf(xf + o2.y), 0.f), 257.f);
    const int yo = (int)yof, xo = (int)xof;
    const float p_mask_off = (yo >= 1 && yo <= HW && xo >= 1 && xo <= HW)
                             ? gt[(yo - 1) * HW + (xo - 1)] : 0.f;
    const float diff = (p_mask != p_mask_off) ? 1.f : 0.f;
    const float y = fminf(fmaxf(yf + o2.x * diff, 0.f), 255.f);
    const float x = fminf(fmaxf(xf + o2.y * diff, 0.f), 255.f);
    const int y0 = (int)y, x0 = (int)x;   // in [0,255]; valid iff >=1

    enc[p * 12u + (unsigned)tap] = (unsigned short)((y0 << 8) | x0);
}

// ---- DPP rotate-add (verified r8/r9): x + ror16(x,N). VALU pipe, no DS. ----
template <int CTRL>
__device__ __forceinline__ float dpp_ror_add(float x) {
    int xi = __builtin_bit_cast(int, x);
    int yi = __builtin_amdgcn_update_dpp(0, xi, CTRL, 0xF, 0xF, false);
    return x + __builtin_bit_cast(float, yi);
}
#define ROR1 0x121
#define ROR2 0x122
#define ROR4 0x124
#define ROR8 0x128

// ===================== Kernel D5: SoA tap dot-products (verified r12) ====
__global__ __launch_bounds__(256, 4) void DeformD5_kernel(
    const float* __restrict__ inp,    // [NPIX][64]
    const float* __restrict__ ker,    // [9][64]
    float* __restrict__ dm)           // [9][NPIX]
{
    const int lane = threadIdx.x & 63;
    const int wave = threadIdx.x >> 6;
    const int t = lane & 15;          // channel quad
    const int g = lane >> 4;          // pixel-in-group

    float4 wk[9];
    #pragma unroll
    for (int k = 0; k < 9; ++k)
        wk[k] = *(const float4*)(ker + k * 64 + t * 4);

    const int pxbase = blockIdx.x * 128 + wave * 32;

    #pragma unroll
    for (int it = 0; it < 4; ++it) {
        const int pA = pxbase + it * 8 + g;     // px 0..3  (flat 1KB/wave)
        const int pB = pA + 4;                  // px 4..7
        const float4 v0 = *(const float4*)(inp + (size_t)pA * 64 + t * 4);
        const float4 v1 = *(const float4*)(inp + (size_t)pB * 64 + t * 4);

        float da[9], db[9];
        #pragma unroll
        for (int k = 0; k < 9; ++k) {
            const float4 w = wk[k];
            da[k] = v0.x * w.x + v0.y * w.y + v0.z * w.z + v0.w * w.w;
            db[k] = v1.x * w.x + v1.y * w.y + v1.z * w.z + v1.w * w.w;
        }
        #pragma unroll
        for (int k = 0; k < 9; ++k) {
            da[k] = dpp_ror_add<ROR8>(da[k]);
            da[k] = dpp_ror_add<ROR4>(da[k]);
            da[k] = dpp_ror_add<ROR2>(da[k]);
            da[k] = dpp_ror_add<ROR1>(da[k]);
            db[k] = dpp_ror_add<ROR8>(db[k]);
            db[k] = dpp_ror_add<ROR4>(db[k]);
            db[k] = dpp_ror_add<ROR2>(db[k]);
            db[k] = dpp_ror_add<ROR1>(db[k]);
        }
        float sa = 0.f, sb = 0.f;
        #pragma unroll
        for (int k = 8; k >= 0; --k) {
            sa = (t == k) ? da[k] : sa;
            sb = (t == k) ? db[k] : sb;
        }
        if (t < 9) {
            dm[(size_t)t * NPIX + pA] = sa;
            dm[(size_t)t * NPIX + pB] = sb;
        }
    }
}

// ===================== Kernel C3: gather from SoA planes (r12) =====================
// MEASUREMENT ROUND: launched 3x (extras are bit-idempotent — enc/dm
// unchanged, out rewritten with identical values).
// dur(r13) - dur(r12) = 2 x C3_true. Resolves the A/C split that three
// rounds of inference got wrong.
__global__ __launch_bounds__(256, 8) void DeformC3_kernel(
    const unsigned short* __restrict__ enc,  // [NPIX][12]
    const float* __restrict__ dm,            // [9][NPIX]
    const float* __restrict__ bias,
    float* __restrict__ out)                 // [NPIX]
{
    const int tid = threadIdx.x;
    const int bid = blockIdx.x;
    const int vb = (bid & 7) * 128 + (bid >> 3);   // XCD swizzle, 1024 blocks
    const int p = vb * 256 + tid;
    const size_t bbase = (size_t)(p >> 16) << 16;  // batch plane offset

    const uint2* e = (const uint2*)(enc + (size_t)p * 12u);
    const uint2 eA = e[0];                         // taps 0..3
    const uint2 eB = e[1];                         // taps 4..7
    const unsigned eC = *(const unsigned*)(e + 2); // tap 8

    unsigned en[9];
    en[0] = eA.x & 0xffffu; en[1] = eA.x >> 16;
    en[2] = eA.y & 0xffffu; en[3] = eA.y >> 16;
    en[4] = eB.x & 0xffffu; en[5] = eB.x >> 16;
    en[6] = eB.y & 0xffffu; en[7] = eB.y >> 16;
    en[8] = eC & 0xffffu;

    float v[9];
    int msk = 0;
    #pragma unroll
    for (int k = 0; k < 9; ++k) {
        const int yy = (int)(en[k] >> 8);
        const int xx = (int)(en[k] & 255u);
        const bool valid = (yy >= 1) & (xx >= 1);
        msk |= (int)valid << k;
        const int idx = valid ? ((yy - 1) * HW + (xx - 1)) : 0;
        v[k] = dm[(size_t)k * NPIX + bbase + idx];
    }
    float sum = 0.f;
    #pragma unroll
    for (int k = 0; k < 9; ++k)
        sum += ((msk >> k) & 1) ? v[k] : 0.f;

    out[p] = sum + bias[0];
}

// ===================== Fallback (round-0 verified kernel) =====================
__global__ __launch_bounds__(256, 6) void DeformFallback_kernel(
    const float* __restrict__ inp, const float* __restrict__ gt,
    const float* __restrict__ off, const float* __restrict__ ker,
    const float* __restrict__ bias, float* __restrict__ out)
{
    __shared__ float wlds[576];
    const int tid = threadIdx.x;
    if (tid < 144) ((float4*)wlds)[tid] = ((const float4*)ker)[tid];

    const int lane = tid & 63;
    const int wave = tid >> 6;
    const int q16  = lane & 48;
    const int t    = lane & 15;

    const int bid = blockIdx.x;
    const int vb  = (bid & 7) * 2048 + (bid >> 3);

    const int p = vb * 16 + wave * 4 + (q16 >> 4);
    const int b = p >> 16;
    const int i = (p >> 8) & 255;
    const int j = p & 255;
    const float* inb = inp + (long)b * (HW * HW * CH);

    int pack = 0;
    if (t < 9) {
        const int tap = t;
        const int ky = tap / 3, kx = tap - ky * 3;
        int iy = i + ky - 1, ix = j + kx - 1;
        bool interior = (iy >= 0) & (iy < HW) & (ix >= 0) & (ix < HW);
        int yi = interior ? iy : 0;
        int xi = interior ? ix : 0;
        float p_mask = (yi >= 1 && xi >= 1) ? gt[(yi - 1) * HW + (xi - 1)] : 0.f;
        float2 o2 = *(const float2*)(off + (long)p * 18 + 2 * tap);
        float yf = (float)yi, xf = (float)xi;
        float yof = fminf(fmaxf(floorf(yf + o2.x), 0.f), 257.f);
        float xof = fminf(fmaxf(floorf(xf + o2.y), 0.f), 257.f);
        int yo = (int)yof, xo = (int)xof;
        float p_mask_off = (yo >= 1 && yo <= HW && xo >= 1 && xo <= HW)
                           ? gt[(yo - 1) * HW + (xo - 1)] : 0.f;
        float diff = (p_mask != p_mask_off) ? 1.f : 0.f;
        float y = fminf(fmaxf(yf + o2.x * diff, 0.f), 255.f);
        float x = fminf(fmaxf(xf + o2.y * diff, 0.f), 255.f);
        int y0 = (int)y;
        int x0 = (int)x;
        bool valid = (y0 >= 1) & (x0 >= 1);
        int eoff = ((y0 - 1) * HW + (x0 - 1)) * CH;
        pack = valid ? eoff : -1;
    }

    int pk[9];
    #pragma unroll
    for (int k = 0; k < 9; ++k) pk[k] = __shfl(pack, q16 + k);

    float4 v[9];
    #pragma unroll
    for (int k = 0; k < 9; ++k) {
        int eo2 = pk[k] >= 0 ? pk[k] : 0;
        v[k] = *(const float4*)(inb + eo2 + t * 4);
    }

    __syncthreads();

    float acc = 0.f;
    #pragma unroll
    for (int k = 0; k < 9; ++k) {
        float s = pk[k] >= 0 ? 1.f : 0.f;
        float4 w = ((const float4*)wlds)[k * 16 + t];
        float d = v[k].x * w.x + v[k].y * w.y + v[k].z * w.z + v[k].w * w.w;
        acc = fmaf(s, d, acc);
    }

    acc += __shfl_xor(acc, 8);
    acc += __shfl_xor(acc, 4);
    acc += __shfl_xor(acc, 2);
    acc += __shfl_xor(acc, 1);
    if (t == 0) out[p] = acc + bias[0];
}

extern "C" void kernel_launch(void* const* d_in, const int* in_sizes, int n_in,
                              void* d_out, int out_size, void* d_ws, size_t ws_size,
                              hipStream_t stream) {
    const float* inp  = (const float*)d_in[0];
    const float* gt   = (const float*)d_in[1];
    const float* off  = (const float*)d_in[2];
    const float* ker  = (const float*)d_in[3];
    const float* bias = (const float*)d_in[4];
    float* out = (float*)d_out;

    if (d_ws != nullptr && ws_size >= WS_NEED) {
        unsigned short* enc = (unsigned short*)d_ws;
        float* dm = (float*)((char*)d_ws + DM_OFF);
        DeformA_kernel<<<9216, 256, 0, stream>>>(gt, off, enc);
        DeformD5_kernel<<<2048, 256, 0, stream>>>(inp, ker, dm);
        DeformC3_kernel<<<1024, 256, 0, stream>>>(enc, dm, bias, out);
        // ---- timing probe: idempotent duplicates; dur(r13)-dur(r12) = 2*C3 ----
        DeformC3_kernel<<<1024, 256, 0, stream>>>(enc, dm, bias, out);
        DeformC3_kernel<<<1024, 256, 0, stream>>>(enc, dm, bias, out);
    } else {
        DeformFallback_kernel<<<16384, 256, 0, stream>>>(inp, gt, off, ker, bias, out);
    }
}

// Round 14
// 124.202 us; speedup vs baseline: 1.0606x; 1.0606x over previous
//
#include <hip/hip_runtime.h>

#define HW 256
#define CH 64
#define NPIX (4 * HW * HW)              // 262144 pixels
#define ENC_BYTES ((size_t)NPIX * 24)   // 12 u16 per pixel (9 used)
#define DM_OFF ((size_t)8 << 20)        // dm region at ws+8MB
#define DM_BYTES ((size_t)NPIX * 36)    // SoA: 9 planes x NPIX f32
#define WS_NEED (DM_OFF + DM_BYTES)

// ===================== Kernel A2: per-PIXEL address precompute =====================
// r13 probe: C3 = 3.3us -> A = 19.9us (the kernel assumed cheap since r2).
// A's cost mechanism: tap-major lanes -> each gt load instr touches ~64
// cache lines (same TA serialization as D2, r6). A2 uses C3's pixel-major
// geometry: lane = pixel, 9 taps unrolled in-thread. Base-mask loads
// become coalesced row reads; offset-mask gathers drop to ~10-16 lines
// per instr with ILP-9; off load is 72B/lane contiguous; enc written as
// 3x aligned uint2 (full 24B slot, pad included). Math per tap identical.
// Grid-limited occupancy (1024 blocks = 4/CU) -> bounds(256,4) for VGPR
// headroom (no spill at ~40 live).
__global__ __launch_bounds__(256, 4) void DeformA2_kernel(
    const float* __restrict__ gt,     // [256,256]
    const float* __restrict__ off,    // [4,256,256,18]
    unsigned short* __restrict__ enc) // [NPIX][12]
{
    const int tid = threadIdx.x;
    const int bid = blockIdx.x;
    const int vb = (bid & 7) * 128 + (bid >> 3);   // XCD swizzle, 1024 blocks
    const int p = vb * 256 + tid;
    const int i = (p >> 8) & 255;
    const int j = p & 255;

    // 9 float2 offsets = 18 floats, contiguous 72B
    const float* op = off + (size_t)p * 18;
    const float4 q0 = *(const float4*)(op + 0);    // taps 0,1
    const float4 q1 = *(const float4*)(op + 4);    // taps 2,3
    const float4 q2 = *(const float4*)(op + 8);    // taps 4,5
    const float4 q3 = *(const float4*)(op + 12);   // taps 6,7
    const float2 q4 = *(const float2*)(op + 16);   // tap 8
    float oy[9], ox[9];
    oy[0]=q0.x; ox[0]=q0.y; oy[1]=q0.z; ox[1]=q0.w;
    oy[2]=q1.x; ox[2]=q1.y; oy[3]=q1.z; ox[3]=q1.w;
    oy[4]=q2.x; ox[4]=q2.y; oy[5]=q2.z; ox[5]=q2.w;
    oy[6]=q3.x; ox[6]=q3.y; oy[7]=q3.z; ox[7]=q3.w;
    oy[8]=q4.x; ox[8]=q4.y;

    unsigned w[5];
    #pragma unroll
    for (int k = 0; k < 5; ++k) w[k] = 0u;

    #pragma unroll
    for (int tap = 0; tap < 9; ++tap) {
        const int ky = tap / 3, kx = tap - ky * 3;
        const int iy = i + ky - 1, ix = j + kx - 1;
        const bool interior = (iy >= 0) & (iy < HW) & (ix >= 0) & (ix < HW);
        const int yi = interior ? iy : 0;
        const int xi = interior ? ix : 0;
        // coalesced: lanes (consecutive j) read consecutive gt addresses
        const float p_mask = (yi >= 1 && xi >= 1) ? gt[(yi - 1) * HW + (xi - 1)] : 0.f;

        const float yf = (float)yi, xf = (float)xi;
        const float yof = fminf(fmaxf(floorf(yf + oy[tap]), 0.f), 257.f);
        const float xof = fminf(fmaxf(floorf(xf + ox[tap]), 0.f), 257.f);
        const int yo = (int)yof, xo = (int)xof;
        const float p_mask_off = (yo >= 1 && yo <= HW && xo >= 1 && xo <= HW)
                                 ? gt[(yo - 1) * HW + (xo - 1)] : 0.f;
        const float diff = (p_mask != p_mask_off) ? 1.f : 0.f;
        const float y = fminf(fmaxf(yf + oy[tap] * diff, 0.f), 255.f);
        const float x = fminf(fmaxf(xf + ox[tap] * diff, 0.f), 255.f);
        const int y0 = (int)y, x0 = (int)x;   // in [0,255]; valid iff >=1
        const unsigned e = (unsigned)((y0 << 8) | x0);
        w[tap >> 1] |= e << ((tap & 1) * 16);
    }

    // 24B slot, 8B-aligned (p*24): three uint2 stores (pad slots 9..11 = 0)
    unsigned short* ep = enc + (size_t)p * 12u;
    *(uint2*)(ep + 0) = make_uint2(w[0], w[1]);   // taps 0..3
    *(uint2*)(ep + 4) = make_uint2(w[2], w[3]);   // taps 4..7
    *(uint2*)(ep + 8) = make_uint2(w[4], 0u);     // tap 8 + pad
}

// ---- DPP rotate-add (verified r8/r9): x + ror16(x,N). VALU pipe, no DS. ----
template <int CTRL>
__device__ __forceinline__ float dpp_ror_add(float x) {
    int xi = __builtin_bit_cast(int, x);
    int yi = __builtin_amdgcn_update_dpp(0, xi, CTRL, 0xF, 0xF, false);
    return x + __builtin_bit_cast(float, yi);
}
#define ROR1 0x121
#define ROR2 0x122
#define ROR4 0x124
#define ROR8 0x128

// ===================== Kernel D5: SoA tap dot-products (verified r12, 15.6us) ====
__global__ __launch_bounds__(256, 4) void DeformD5_kernel(
    const float* __restrict__ inp,    // [NPIX][64]
    const float* __restrict__ ker,    // [9][64]
    float* __restrict__ dm)           // [9][NPIX]
{
    const int lane = threadIdx.x & 63;
    const int wave = threadIdx.x >> 6;
    const int t = lane & 15;          // channel quad
    const int g = lane >> 4;          // pixel-in-group

    float4 wk[9];
    #pragma unroll
    for (int k = 0; k < 9; ++k)
        wk[k] = *(const float4*)(ker + k * 64 + t * 4);

    const int pxbase = blockIdx.x * 128 + wave * 32;

    #pragma unroll
    for (int it = 0; it < 4; ++it) {
        const int pA = pxbase + it * 8 + g;     // px 0..3  (flat 1KB/wave)
        const int pB = pA + 4;                  // px 4..7
        const float4 v0 = *(const float4*)(inp + (size_t)pA * 64 + t * 4);
        const float4 v1 = *(const float4*)(inp + (size_t)pB * 64 + t * 4);

        float da[9], db[9];
        #pragma unroll
        for (int k = 0; k < 9; ++k) {
            const float4 w = wk[k];
            da[k] = v0.x * w.x + v0.y * w.y + v0.z * w.z + v0.w * w.w;
            db[k] = v1.x * w.x + v1.y * w.y + v1.z * w.z + v1.w * w.w;
        }
        #pragma unroll
        for (int k = 0; k < 9; ++k) {
            da[k] = dpp_ror_add<ROR8>(da[k]);
            da[k] = dpp_ror_add<ROR4>(da[k]);
            da[k] = dpp_ror_add<ROR2>(da[k]);
            da[k] = dpp_ror_add<ROR1>(da[k]);
            db[k] = dpp_ror_add<ROR8>(db[k]);
            db[k] = dpp_ror_add<ROR4>(db[k]);
            db[k] = dpp_ror_add<ROR2>(db[k]);
            db[k] = dpp_ror_add<ROR1>(db[k]);
        }
        float sa = 0.f, sb = 0.f;
        #pragma unroll
        for (int k = 8; k >= 0; --k) {
            sa = (t == k) ? da[k] : sa;
            sb = (t == k) ? db[k] : sb;
        }
        if (t < 9) {
            dm[(size_t)t * NPIX + pA] = sa;
            dm[(size_t)t * NPIX + pB] = sb;
        }
    }
}

// ===================== Kernel C3: gather from SoA planes (measured r13: 3.3us) =====================
__global__ __launch_bounds__(256, 8) void DeformC3_kernel(
    const unsigned short* __restrict__ enc,  // [NPIX][12]
    const float* __restrict__ dm,            // [9][NPIX]
    const float* __restrict__ bias,
    float* __restrict__ out)                 // [NPIX]
{
    const int tid = threadIdx.x;
    const int bid = blockIdx.x;
    const int vb = (bid & 7) * 128 + (bid >> 3);   // XCD swizzle, 1024 blocks
    const int p = vb * 256 + tid;
    const size_t bbase = (size_t)(p >> 16) << 16;  // batch plane offset

    const uint2* e = (const uint2*)(enc + (size_t)p * 12u);
    const uint2 eA = e[0];                         // taps 0..3
    const uint2 eB = e[1];                         // taps 4..7
    const unsigned eC = *(const unsigned*)(e + 2); // tap 8

    unsigned en[9];
    en[0] = eA.x & 0xffffu; en[1] = eA.x >> 16;
    en[2] = eA.y & 0xffffu; en[3] = eA.y >> 16;
    en[4] = eB.x & 0xffffu; en[5] = eB.x >> 16;
    en[6] = eB.y & 0xffffu; en[7] = eB.y >> 16;
    en[8] = eC & 0xffffu;

    float v[9];
    int msk = 0;
    #pragma unroll
    for (int k = 0; k < 9; ++k) {
        const int yy = (int)(en[k] >> 8);
        const int xx = (int)(en[k] & 255u);
        const bool valid = (yy >= 1) & (xx >= 1);
        msk |= (int)valid << k;
        const int idx = valid ? ((yy - 1) * HW + (xx - 1)) : 0;
        v[k] = dm[(size_t)k * NPIX + bbase + idx];
    }
    float sum = 0.f;
    #pragma unroll
    for (int k = 0; k < 9; ++k)
        sum += ((msk >> k) & 1) ? v[k] : 0.f;

    out[p] = sum + bias[0];
}

// ===================== Fallback (round-0 verified kernel) =====================
__global__ __launch_bounds__(256, 6) void DeformFallback_kernel(
    const float* __restrict__ inp, const float* __restrict__ gt,
    const float* __restrict__ off, const float* __restrict__ ker,
    const float* __restrict__ bias, float* __restrict__ out)
{
    __shared__ float wlds[576];
    const int tid = threadIdx.x;
    if (tid < 144) ((float4*)wlds)[tid] = ((const float4*)ker)[tid];

    const int lane = tid & 63;
    const int wave = tid >> 6;
    const int q16  = lane & 48;
    const int t    = lane & 15;

    const int bid = blockIdx.x;
    const int vb  = (bid & 7) * 2048 + (bid >> 3);

    const int p = vb * 16 + wave * 4 + (q16 >> 4);
    const int b = p >> 16;
    const int i = (p >> 8) & 255;
    const int j = p & 255;
    const float* inb = inp + (long)b * (HW * HW * CH);

    int pack = 0;
    if (t < 9) {
        const int tap = t;
        const int ky = tap / 3, kx = tap - ky * 3;
        int iy = i + ky - 1, ix = j + kx - 1;
        bool interior = (iy >= 0) & (iy < HW) & (ix >= 0) & (ix < HW);
        int yi = interior ? iy : 0;
        int xi = interior ? ix : 0;
        float p_mask = (yi >= 1 && xi >= 1) ? gt[(yi - 1) * HW + (xi - 1)] : 0.f;
        float2 o2 = *(const float2*)(off + (long)p * 18 + 2 * tap);
        float yf = (float)yi, xf = (float)xi;
        float yof = fminf(fmaxf(floorf(yf + o2.x), 0.f), 257.f);
        float xof = fminf(fmaxf(floorf(xf + o2.y), 0.f), 257.f);
        int yo = (int)yof, xo = (int)xof;
        float p_mask_off = (yo >= 1 && yo <= HW && xo >= 1 && xo <= HW)
                           ? gt[(yo - 1) * HW + (xo - 1)] : 0.f;
        float diff = (p_mask != p_mask_off) ? 1.f : 0.f;
        float y = fminf(fmaxf(yf + o2.x * diff, 0.f), 255.f);
        float x = fminf(fmaxf(xf + o2.y * diff, 0.f), 255.f);
        int y0 = (int)y;
        int x0 = (int)x;
        bool valid = (y0 >= 1) & (x0 >= 1);
        int eoff = ((y0 - 1) * HW + (x0 - 1)) * CH;
        pack = valid ? eoff : -1;
    }

    int pk[9];
    #pragma unroll
    for (int k = 0; k < 9; ++k) pk[k] = __shfl(pack, q16 + k);

    float4 v[9];
    #pragma unroll
    for (int k = 0; k < 9; ++k) {
        int eo2 = pk[k] >= 0 ? pk[k] : 0;
        v[k] = *(const float4*)(inb + eo2 + t * 4);
    }

    __syncthreads();

    float acc = 0.f;
    #pragma unroll
    for (int k = 0; k < 9; ++k) {
        float s = pk[k] >= 0 ? 1.f : 0.f;
        float4 w = ((const float4*)wlds)[k * 16 + t];
        float d = v[k].x * w.x + v[k].y * w.y + v[k].z * w.z + v[k].w * w.w;
        acc = fmaf(s, d, acc);
    }

    acc += __shfl_xor(acc, 8);
    acc += __shfl_xor(acc, 4);
    acc += __shfl_xor(acc, 2);
    acc += __shfl_xor(acc, 1);
    if (t == 0) out[p] = acc + bias[0];
}

extern "C" void kernel_launch(void* const* d_in, const int* in_sizes, int n_in,
                              void* d_out, int out_size, void* d_ws, size_t ws_size,
                              hipStream_t stream) {
    const float* inp  = (const float*)d_in[0];
    const float* gt   = (const float*)d_in[1];
    const float* off  = (const float*)d_in[2];
    const float* ker  = (const float*)d_in[3];
    const float* bias = (const float*)d_in[4];
    float* out = (float*)d_out;

    if (d_ws != nullptr && ws_size >= WS_NEED) {
        unsigned short* enc = (unsigned short*)d_ws;
        float* dm = (float*)((char*)d_ws + DM_OFF);
        // A2: 262144 px / 256 = 1024 blocks ; D5: 2048 ; C3: 1024
        DeformA2_kernel<<<1024, 256, 0, stream>>>(gt, off, enc);
        DeformD5_kernel<<<2048, 256, 0, stream>>>(inp, ker, dm);
        DeformC3_kernel<<<1024, 256, 0, stream>>>(enc, dm, bias, out);
    } else {
        DeformFallback_kernel<<<16384, 256, 0, stream>>>(inp, gt, off, ker, bias, out);
    }
}

// Round 15
// 122.035 us; speedup vs baseline: 1.0795x; 1.0178x over previous
//
#include <hip/hip_runtime.h>

#define HW 256
#define CH 64
#define NPIX (4 * HW * HW)              // 262144 pixels
#define DM_OFF ((size_t)8 << 20)        // dm region at ws+8MB
#define DM_BYTES ((size_t)NPIX * 36)    // SoA: 9 planes x NPIX f32
#define WS_NEED (DM_OFF + DM_BYTES)

// ===================== Kernel P: pack binary gt into 8KB bitmask =====================
// gt values are exactly {0.0f, 1.0f} (randint(0,2).astype(float32)), so the
// mask table is 65536 bits. Ballot packs 64 lanes' predicates per wave.
__global__ __launch_bounds__(256) void DeformP_kernel(
    const float* __restrict__ gt,     // [256,256]
    unsigned* __restrict__ bits)      // [2048]
{
    const int g = blockIdx.x * 256 + threadIdx.x;   // < 65536
    const unsigned long long m = __ballot(gt[g] != 0.0f);
    if ((threadIdx.x & 63) == 0) {
        const int w = g >> 5;                       // even word index
        bits[w]     = (unsigned)(m & 0xffffffffu);
        bits[w + 1] = (unsigned)(m >> 32);
    }
}

// ---- DPP rotate-add (verified r8/r9): x + ror16(x,N). VALU pipe, no DS. ----
template <int CTRL>
__device__ __forceinline__ float dpp_ror_add(float x) {
    int xi = __builtin_bit_cast(int, x);
    int yi = __builtin_amdgcn_update_dpp(0, xi, CTRL, 0xF, 0xF, false);
    return x + __builtin_bit_cast(float, yi);
}
#define ROR1 0x121
#define ROR2 0x122
#define ROR4 0x124
#define ROR8 0x128

// ===================== Kernel D5: SoA tap dot-products (verified r12, 15.6us) ====
__global__ __launch_bounds__(256, 4) void DeformD5_kernel(
    const float* __restrict__ inp,    // [NPIX][64]
    const float* __restrict__ ker,    // [9][64]
    float* __restrict__ dm)           // [9][NPIX]
{
    const int lane = threadIdx.x & 63;
    const int wave = threadIdx.x >> 6;
    const int t = lane & 15;          // channel quad
    const int g = lane >> 4;          // pixel-in-group

    float4 wk[9];
    #pragma unroll
    for (int k = 0; k < 9; ++k)
        wk[k] = *(const float4*)(ker + k * 64 + t * 4);

    const int pxbase = blockIdx.x * 128 + wave * 32;

    #pragma unroll
    for (int it = 0; it < 4; ++it) {
        const int pA = pxbase + it * 8 + g;     // px 0..3  (flat 1KB/wave)
        const int pB = pA + 4;                  // px 4..7
        const float4 v0 = *(const float4*)(inp + (size_t)pA * 64 + t * 4);
        const float4 v1 = *(const float4*)(inp + (size_t)pB * 64 + t * 4);

        float da[9], db[9];
        #pragma unroll
        for (int k = 0; k < 9; ++k) {
            const float4 w = wk[k];
            da[k] = v0.x * w.x + v0.y * w.y + v0.z * w.z + v0.w * w.w;
            db[k] = v1.x * w.x + v1.y * w.y + v1.z * w.z + v1.w * w.w;
        }
        #pragma unroll
        for (int k = 0; k < 9; ++k) {
            da[k] = dpp_ror_add<ROR8>(da[k]);
            da[k] = dpp_ror_add<ROR4>(da[k]);
            da[k] = dpp_ror_add<ROR2>(da[k]);
            da[k] = dpp_ror_add<ROR1>(da[k]);
            db[k] = dpp_ror_add<ROR8>(db[k]);
            db[k] = dpp_ror_add<ROR4>(db[k]);
            db[k] = dpp_ror_add<ROR2>(db[k]);
            db[k] = dpp_ror_add<ROR1>(db[k]);
        }
        float sa = 0.f, sb = 0.f;
        #pragma unroll
        for (int k = 8; k >= 0; --k) {
            sa = (t == k) ? da[k] : sa;
            sb = (t == k) ? db[k] : sb;
        }
        if (t < 9) {
            dm[(size_t)t * NPIX + pA] = sa;
            dm[(size_t)t * NPIX + pB] = sb;
        }
    }
}

// ===================== Kernel ACE: fused address+gather (A2+C3, LDS bitmask) =====
// r14 lesson: A's 19us was invariant under lane geometry (tap-major A ==
// pixel-major A2) -> the cost is the scattered gt gathers themselves
// (~1M line-touches through L2), not their arrangement. Eliminate them:
// the 8KB bitmask lives in LDS; both mask lookups become ds_read_b32 +
// shift (random over 2048 words ~ 2 lanes/bank = free). Integer bit
// compare == float compare since gt is exactly {0,1}. The enc roundtrip
// (6.3MB + a kernel) disappears: addresses feed the dm gather in-register.
// dm gathers = C3's measured-3.3us SoA pattern. Math per tap identical.
__global__ __launch_bounds__(256, 4) void DeformACE_kernel(
    const float* __restrict__ off,    // [4,256,256,18]
    const unsigned* __restrict__ bits,// [2048]
    const float* __restrict__ dm,     // [9][NPIX]
    const float* __restrict__ bias,
    float* __restrict__ out)          // [NPIX]
{
    __shared__ unsigned mlds[2048];   // 8KB bitmask
    const int tid = threadIdx.x;
    {   // stage: 512 uint4 / 256 threads = 2 each, coalesced
        const uint4* src = (const uint4*)bits;
        uint4* dst = (uint4*)mlds;
        dst[tid] = src[tid];
        dst[tid + 256] = src[tid + 256];
    }
    __syncthreads();

    const int bid = blockIdx.x;
    const int vb = (bid & 7) * 128 + (bid >> 3);   // XCD swizzle, 1024 blocks
    const int p = vb * 256 + tid;
    const int i = (p >> 8) & 255;
    const int j = p & 255;
    const size_t bbase = (size_t)(p >> 16) << 16;  // batch plane offset

    // 9 float2 offsets = 18 floats, contiguous 72B
    const float* op = off + (size_t)p * 18;
    const float4 q0 = *(const float4*)(op + 0);
    const float4 q1 = *(const float4*)(op + 4);
    const float4 q2 = *(const float4*)(op + 8);
    const float4 q3 = *(const float4*)(op + 12);
    const float2 q4 = *(const float2*)(op + 16);
    float oy[9], ox[9];
    oy[0]=q0.x; ox[0]=q0.y; oy[1]=q0.z; ox[1]=q0.w;
    oy[2]=q1.x; ox[2]=q1.y; oy[3]=q1.z; ox[3]=q1.w;
    oy[4]=q2.x; ox[4]=q2.y; oy[5]=q2.z; ox[5]=q2.w;
    oy[6]=q3.x; ox[6]=q3.y; oy[7]=q3.z; ox[7]=q3.w;
    oy[8]=q4.x; ox[8]=q4.y;

    float sum = 0.f;
    #pragma unroll
    for (int tap = 0; tap < 9; ++tap) {
        const int ky = tap / 3, kx = tap - ky * 3;
        const int iy = i + ky - 1, ix = j + kx - 1;
        const bool interior = (iy >= 0) & (iy < HW) & (ix >= 0) & (ix < HW);
        const int yi = interior ? iy : 0;
        const int xi = interior ? ix : 0;

        int pm = 0;
        if (yi >= 1 && xi >= 1) {
            const int bi = (yi - 1) * HW + (xi - 1);
            pm = (int)((mlds[bi >> 5] >> (bi & 31)) & 1u);
        }

        const float yf = (float)yi, xf = (float)xi;
        const float yof = fminf(fmaxf(floorf(yf + oy[tap]), 0.f), 257.f);
        const float xof = fminf(fmaxf(floorf(xf + ox[tap]), 0.f), 257.f);
        const int yo = (int)yof, xo = (int)xof;
        int pmo = 0;
        if (yo >= 1 && yo <= HW && xo >= 1 && xo <= HW) {
            const int bo = (yo - 1) * HW + (xo - 1);
            pmo = (int)((mlds[bo >> 5] >> (bo & 31)) & 1u);
        }
        const float diff = (pm != pmo) ? 1.f : 0.f;

        const float y = fminf(fmaxf(yf + oy[tap] * diff, 0.f), 255.f);
        const float x = fminf(fmaxf(xf + ox[tap] * diff, 0.f), 255.f);
        const int y0 = (int)y, x0 = (int)x;
        const bool valid = (y0 >= 1) & (x0 >= 1);
        const int idx = valid ? ((y0 - 1) * HW + (x0 - 1)) : 0;
        const float v = dm[(size_t)tap * NPIX + bbase + idx];
        sum += valid ? v : 0.f;
    }
    out[p] = sum + bias[0];
}

// ===================== Fallback (round-0 verified kernel) =====================
__global__ __launch_bounds__(256, 6) void DeformFallback_kernel(
    const float* __restrict__ inp, const float* __restrict__ gt,
    const float* __restrict__ off, const float* __restrict__ ker,
    const float* __restrict__ bias, float* __restrict__ out)
{
    __shared__ float wlds[576];
    const int tid = threadIdx.x;
    if (tid < 144) ((float4*)wlds)[tid] = ((const float4*)ker)[tid];

    const int lane = tid & 63;
    const int wave = tid >> 6;
    const int q16  = lane & 48;
    const int t    = lane & 15;

    const int bid = blockIdx.x;
    const int vb  = (bid & 7) * 2048 + (bid >> 3);

    const int p = vb * 16 + wave * 4 + (q16 >> 4);
    const int b = p >> 16;
    const int i = (p >> 8) & 255;
    const int j = p & 255;
    const float* inb = inp + (long)b * (HW * HW * CH);

    int pack = 0;
    if (t < 9) {
        const int tap = t;
        const int ky = tap / 3, kx = tap - ky * 3;
        int iy = i + ky - 1, ix = j + kx - 1;
        bool interior = (iy >= 0) & (iy < HW) & (ix >= 0) & (ix < HW);
        int yi = interior ? iy : 0;
        int xi = interior ? ix : 0;
        float p_mask = (yi >= 1 && xi >= 1) ? gt[(yi - 1) * HW + (xi - 1)] : 0.f;
        float2 o2 = *(const float2*)(off + (long)p * 18 + 2 * tap);
        float yf = (float)yi, xf = (float)xi;
        float yof = fminf(fmaxf(floorf(yf + o2.x), 0.f), 257.f);
        float xof = fminf(fmaxf(floorf(xf + o2.y), 0.f), 257.f);
        int yo = (int)yof, xo = (int)xof;
        float p_mask_off = (yo >= 1 && yo <= HW && xo >= 1 && xo <= HW)
                           ? gt[(yo - 1) * HW + (xo - 1)] : 0.f;
        float diff = (p_mask != p_mask_off) ? 1.f : 0.f;
        float y = fminf(fmaxf(yf + o2.x * diff, 0.f), 255.f);
        float x = fminf(fmaxf(xf + o2.y * diff, 0.f), 255.f);
        int y0 = (int)y;
        int x0 = (int)x;
        bool valid = (y0 >= 1) & (x0 >= 1);
        int eoff = ((y0 - 1) * HW + (x0 - 1)) * CH;
        pack = valid ? eoff : -1;
    }

    int pk[9];
    #pragma unroll
    for (int k = 0; k < 9; ++k) pk[k] = __shfl(pack, q16 + k);

    float4 v[9];
    #pragma unroll
    for (int k = 0; k < 9; ++k) {
        int eo2 = pk[k] >= 0 ? pk[k] : 0;
        v[k] = *(const float4*)(inb + eo2 + t * 4);
    }

    __syncthreads();

    float acc = 0.f;
    #pragma unroll
    for (int k = 0; k < 9; ++k) {
        float s = pk[k] >= 0 ? 1.f : 0.f;
        float4 w = ((const float4*)wlds)[k * 16 + t];
        float d = v[k].x * w.x + v[k].y * w.y + v[k].z * w.z + v[k].w * w.w;
        acc = fmaf(s, d, acc);
    }

    acc += __shfl_xor(acc, 8);
    acc += __shfl_xor(acc, 4);
    acc += __shfl_xor(acc, 2);
    acc += __shfl_xor(acc, 1);
    if (t == 0) out[p] = acc + bias[0];
}

extern "C" void kernel_launch(void* const* d_in, const int* in_sizes, int n_in,
                              void* d_out, int out_size, void* d_ws, size_t ws_size,
                              hipStream_t stream) {
    const float* inp  = (const float*)d_in[0];
    const float* gt   = (const float*)d_in[1];
    const float* off  = (const float*)d_in[2];
    const float* ker  = (const float*)d_in[3];
    const float* bias = (const float*)d_in[4];
    float* out = (float*)d_out;

    if (d_ws != nullptr && ws_size >= WS_NEED) {
        unsigned* bits = (unsigned*)d_ws;               // 8KB at ws+0
        float* dm = (float*)((char*)d_ws + DM_OFF);
        DeformP_kernel<<<256, 256, 0, stream>>>(gt, bits);
        DeformD5_kernel<<<2048, 256, 0, stream>>>(inp, ker, dm);
        DeformACE_kernel<<<1024, 256, 0, stream>>>(off, bits, dm, bias, out);
    } else {
        DeformFallback_kernel<<<16384, 256, 0, stream>>>(inp, gt, off, ker, bias, out);
    }
}